// Round 1
// baseline (1021.157 us; speedup 1.0000x reference)
//
#include <hip/hip_runtime.h>
#include <math.h>

#define N_PTS 8192
#define BATCH 2
#define KNB 16
#define NCHUNK 8
#define CHUNK (N_PTS / NCHUNK)      // 1024
#define NQ (BATCH * N_PTS)          // 16384

// ---------------- Phase 1: partial top-16 per (query, chunk) ----------------
// Block = 256 threads = 256 consecutive queries (same batch, since 8192%256==0),
// blockIdx.y = candidate chunk. Candidates staged in LDS; all lanes read the
// same LDS address each iteration -> broadcast, no bank conflicts.
__global__ __launch_bounds__(256) void knn_partial(const float* __restrict__ pos,
                                                   float* __restrict__ pd,
                                                   int* __restrict__ pi) {
    __shared__ float sx[CHUNK], sy[CHUNK], sz[CHUNK];
    const int tid = threadIdx.x;
    const int qg  = blockIdx.x * 256 + tid;       // global query id [0, NQ)
    const int b   = qg >> 13;                     // batch (N_PTS = 8192)
    const int c   = blockIdx.y;                   // chunk
    const int j0  = c * CHUNK;

    const float* pb = pos + (size_t)b * N_PTS * 3;
    for (int t = tid; t < CHUNK; t += 256) {
        const float* p = pb + (size_t)(j0 + t) * 3;
        sx[t] = p[0]; sy[t] = p[1]; sz[t] = p[2];
    }
    __syncthreads();

    const float qx = pos[qg * 3 + 0];
    const float qy = pos[qg * 3 + 1];
    const float qz = pos[qg * 3 + 2];

    // top-16 smallest; invariant: dist[0] is the MAX of the current 16.
    float dist[KNB]; int idxs[KNB];
#pragma unroll
    for (int s = 0; s < KNB; ++s) { dist[s] = 3.4e38f; idxs[s] = 0; }

#pragma unroll 4
    for (int t = 0; t < CHUNK; ++t) {
        float dx = qx - sx[t], dy = qy - sy[t], dz = qz - sz[t];
        float d2 = fmaf(dx, dx, fmaf(dy, dy, dz * dz));
        if (d2 < dist[0]) {
            dist[0] = d2; idxs[0] = j0 + t;
            // restore invariant: bubble the max back into slot 0 (all static idx)
#pragma unroll
            for (int s = 1; s < KNB; ++s) {
                float a = dist[0], bb = dist[s];
                bool sw = bb > a;
                float na = sw ? bb : a;
                float nb = sw ? a  : bb;
                int ia = idxs[0], ib = idxs[s];
                int nia = sw ? ib : ia;
                int nib = sw ? ia : ib;
                dist[0] = na; dist[s] = nb;
                idxs[0] = nia; idxs[s] = nib;
            }
        }
    }

    // store [slot][query] so phase-2 reads coalesce
#pragma unroll
    for (int s = 0; s < KNB; ++s) {
        pd[(size_t)(c * KNB + s) * NQ + qg] = dist[s];
        pi[(size_t)(c * KNB + s) * NQ + qg] = idxs[s];
    }
}

// ---------------- Phase 2: merge 8x16 partials -> final 16 ----------------
__global__ __launch_bounds__(256) void knn_merge(const float* __restrict__ pd,
                                                 const int* __restrict__ pi,
                                                 int* __restrict__ knn) {
    const int qg = blockIdx.x * 256 + threadIdx.x;

    float dist[KNB]; int idxs[KNB];
#pragma unroll
    for (int s = 0; s < KNB; ++s) { dist[s] = 3.4e38f; idxs[s] = 0; }

    for (int t = 0; t < NCHUNK * KNB; ++t) {
        float d2 = pd[(size_t)t * NQ + qg];
        int   j  = pi[(size_t)t * NQ + qg];
        if (d2 < dist[0]) {
            dist[0] = d2; idxs[0] = j;
#pragma unroll
            for (int s = 1; s < KNB; ++s) {
                float a = dist[0], bb = dist[s];
                bool sw = bb > a;
                float na = sw ? bb : a;
                float nb = sw ? a  : bb;
                int ia = idxs[0], ib = idxs[s];
                int nia = sw ? ib : ia;
                int nib = sw ? ia : ib;
                dist[0] = na; dist[s] = nb;
                idxs[0] = nia; idxs[s] = nib;
            }
        }
    }
#pragma unroll
    for (int s = 0; s < KNB; ++s) knn[(size_t)qg * KNB + s] = idxs[s];
}

// ---------------- PointTransformer layer (thread per point) ----------------
__global__ __launch_bounds__(64) void pt_layer(const float* __restrict__ hin,
                                               const float* __restrict__ pos,
                                               const int* __restrict__ knn,
                                               const float* __restrict__ wqkv,
                                               const float* __restrict__ pw1,
                                               const float* __restrict__ pb1,
                                               const float* __restrict__ pw2,
                                               const float* __restrict__ pb2,
                                               const float* __restrict__ aw1,
                                               const float* __restrict__ ab1,
                                               const float* __restrict__ aw2,
                                               const float* __restrict__ ab2,
                                               float* __restrict__ hout,
                                               const float* __restrict__ lw,
                                               const float* __restrict__ lb,
                                               float* __restrict__ out,
                                               int last) {
    const int qg = blockIdx.x * 64 + threadIdx.x;
    const int b  = qg >> 13;

    const float hi0 = hin[qg * 3 + 0], hi1 = hin[qg * 3 + 1], hi2 = hin[qg * 3 + 2];
    const float px = pos[qg * 3 + 0], py = pos[qg * 3 + 1], pz = pos[qg * 3 + 2];

    // q = h_i @ Wqkv[:, 0:3]
    const float q0 = fmaf(hi0, wqkv[0], fmaf(hi1, wqkv[9],  hi2 * wqkv[18]));
    const float q1 = fmaf(hi0, wqkv[1], fmaf(hi1, wqkv[10], hi2 * wqkv[19]));
    const float q2 = fmaf(hi0, wqkv[2], fmaf(hi1, wqkv[11], hi2 * wqkv[20]));

    float sim[KNB][3], ve[KNB][3];

#pragma unroll
    for (int j = 0; j < KNB; ++j) {
        const int jj = knn[qg * KNB + j];
        const int g  = b * N_PTS + jj;
        const float hj0 = hin[g * 3 + 0], hj1 = hin[g * 3 + 1], hj2 = hin[g * 3 + 2];
        const float ox = pos[g * 3 + 0], oy = pos[g * 3 + 1], oz = pos[g * 3 + 2];
        const float rx = px - ox, ry = py - oy, rz = pz - oz;

        // k_j = h_j @ Wqkv[:, 3:6], v_j = h_j @ Wqkv[:, 6:9]
        const float k0 = fmaf(hj0, wqkv[3], fmaf(hj1, wqkv[12], hj2 * wqkv[21]));
        const float k1 = fmaf(hj0, wqkv[4], fmaf(hj1, wqkv[13], hj2 * wqkv[22]));
        const float k2 = fmaf(hj0, wqkv[5], fmaf(hj1, wqkv[14], hj2 * wqkv[23]));
        const float v0 = fmaf(hj0, wqkv[6], fmaf(hj1, wqkv[15], hj2 * wqkv[24]));
        const float v1 = fmaf(hj0, wqkv[7], fmaf(hj1, wqkv[16], hj2 * wqkv[25]));
        const float v2 = fmaf(hj0, wqkv[8], fmaf(hj1, wqkv[17], hj2 * wqkv[26]));

        // rel_emb = MLP2(rel_pos): 3 -> 32 -> 3
        float e0 = pb2[0], e1 = pb2[1], e2 = pb2[2];
#pragma unroll
        for (int hh = 0; hh < 32; ++hh) {
            float t = fmaf(rx, pw1[hh], fmaf(ry, pw1[32 + hh], fmaf(rz, pw1[64 + hh], pb1[hh])));
            t = fmaxf(t, 0.0f);
            e0 = fmaf(t, pw2[hh * 3 + 0], e0);
            e1 = fmaf(t, pw2[hh * 3 + 1], e1);
            e2 = fmaf(t, pw2[hh * 3 + 2], e2);
        }

        const float x0 = q0 - k0 + e0;
        const float x1 = q1 - k1 + e1;
        const float x2 = q2 - k2 + e2;

        // sim = MLP2(x): 3 -> 12 -> 3
        float s0 = ab2[0], s1 = ab2[1], s2 = ab2[2];
#pragma unroll
        for (int hh = 0; hh < 12; ++hh) {
            float t = fmaf(x0, aw1[hh], fmaf(x1, aw1[12 + hh], fmaf(x2, aw1[24 + hh], ab1[hh])));
            t = fmaxf(t, 0.0f);
            s0 = fmaf(t, aw2[hh * 3 + 0], s0);
            s1 = fmaf(t, aw2[hh * 3 + 1], s1);
            s2 = fmaf(t, aw2[hh * 3 + 2], s2);
        }

        sim[j][0] = s0; sim[j][1] = s1; sim[j][2] = s2;
        ve[j][0] = v0 + e0; ve[j][1] = v1 + e1; ve[j][2] = v2 + e2;
    }

    // softmax over neighbors (per channel) + weighted aggregate + sigmoid
    float hnew[3];
#pragma unroll
    for (int d = 0; d < 3; ++d) {
        float m = sim[0][d];
#pragma unroll
        for (int j = 1; j < KNB; ++j) m = fmaxf(m, sim[j][d]);
        float den = 0.0f, acc = 0.0f;
#pragma unroll
        for (int j = 0; j < KNB; ++j) {
            float e = expf(sim[j][d] - m);
            den += e;
            acc = fmaf(e, ve[j][d], acc);
        }
        float a = acc / den;
        hnew[d] = 1.0f / (1.0f + expf(-a));
    }

    if (!last) {
        hout[qg * 3 + 0] = hnew[0];
        hout[qg * 3 + 1] = hnew[1];
        hout[qg * 3 + 2] = hnew[2];
    } else {
        // out = softmax(h @ lin_w + lin_b) over 2 classes
        float o0 = fmaf(hnew[0], lw[0], fmaf(hnew[1], lw[2], fmaf(hnew[2], lw[4], lb[0])));
        float o1 = fmaf(hnew[0], lw[1], fmaf(hnew[1], lw[3], fmaf(hnew[2], lw[5], lb[1])));
        float mm = fmaxf(o0, o1);
        float e0 = expf(o0 - mm), e1 = expf(o1 - mm);
        float inv = 1.0f / (e0 + e1);
        out[qg * 2 + 0] = e0 * inv;
        out[qg * 2 + 1] = e1 * inv;
    }
}

// ---------------- launch ----------------
extern "C" void kernel_launch(void* const* d_in, const int* in_sizes, int n_in,
                              void* d_out, int out_size, void* d_ws, size_t ws_size,
                              hipStream_t stream) {
    const float* feats = (const float*)d_in[0];
    const float* pos   = (const float*)d_in[1];
    // d_in[2] = mask (unused by reference forward)
    const float* wqkv = (const float*)d_in[3];
    const float* pw1  = (const float*)d_in[4];
    const float* pb1  = (const float*)d_in[5];
    const float* pw2  = (const float*)d_in[6];
    const float* pb2  = (const float*)d_in[7];
    const float* aw1  = (const float*)d_in[8];
    const float* ab1  = (const float*)d_in[9];
    const float* aw2  = (const float*)d_in[10];
    const float* ab2  = (const float*)d_in[11];
    const float* lw   = (const float*)d_in[12];
    const float* lb   = (const float*)d_in[13];
    float* out = (float*)d_out;

    // workspace layout
    const size_t pd_bytes  = (size_t)NCHUNK * KNB * NQ * 4;   // 8 MB
    const size_t pi_bytes  = pd_bytes;                        // 8 MB
    const size_t knn_bytes = (size_t)NQ * KNB * 4;            // 1 MB
    const size_t h_bytes   = (size_t)NQ * 3 * 4;              // 192 KB
    if (ws_size < pd_bytes + pi_bytes + knn_bytes + 2 * h_bytes) return; // fail loudly (validation mismatch)

    char* ws = (char*)d_ws;
    float* pd  = (float*)ws;
    int*   pi  = (int*)(ws + pd_bytes);
    int*   knn = (int*)(ws + pd_bytes + pi_bytes);
    float* hA  = (float*)(ws + pd_bytes + pi_bytes + knn_bytes);
    float* hB  = hA + (size_t)NQ * 3;

    dim3 g1(NQ / 256, NCHUNK);
    knn_partial<<<g1, 256, 0, stream>>>(pos, pd, pi);
    knn_merge<<<NQ / 256, 256, 0, stream>>>(pd, pi, knn);

    // layer 0: feats -> hA
    pt_layer<<<NQ / 64, 64, 0, stream>>>(feats, pos, knn,
        wqkv + 0, pw1 + 0, pb1 + 0, pw2 + 0, pb2 + 0,
        aw1 + 0, ab1 + 0, aw2 + 0, ab2 + 0,
        hA, lw, lb, out, 0);
    // layer 1: hA -> hB
    pt_layer<<<NQ / 64, 64, 0, stream>>>(hA, pos, knn,
        wqkv + 27, pw1 + 96, pb1 + 32, pw2 + 96, pb2 + 3,
        aw1 + 36, ab1 + 12, aw2 + 36, ab2 + 3,
        hB, lw, lb, out, 0);
    // layer 2: hB -> out (fused final linear + softmax)
    pt_layer<<<NQ / 64, 64, 0, stream>>>(hB, pos, knn,
        wqkv + 54, pw1 + 192, pb1 + 64, pw2 + 192, pb2 + 6,
        aw1 + 72, ab1 + 24, aw2 + 72, ab2 + 6,
        hB, lw, lb, out, 1);
}

// Round 2
// 220.348 us; speedup vs baseline: 4.6343x; 4.6343x over previous
//
#include <hip/hip_runtime.h>
#include <math.h>

#define N_PTS 8192
#define BATCH 2
#define KNB 16
#define NCHUNK 8
#define CHUNK (N_PTS / NCHUNK)      // 1024
#define NQ (BATCH * N_PTS)          // 16384
#define FLT_BIG 3.4e38f

__device__ __forceinline__ float med3f(float a, float b, float c) {
#if __has_builtin(__builtin_amdgcn_fmed3f)
    return __builtin_amdgcn_fmed3f(a, b, c);
#else
    return fmaxf(fminf(a, b), fminf(fmaxf(a, b), c));
#endif
}

// Branchless (dist,idx) sorted-insert (descending; d[0]=max). In-place
// ascending s: reads d[s+1]/ix[s+1] before they are overwritten. Static idx only.
__device__ __forceinline__ void ins16(float (&d)[KNB], int (&ix)[KNB], float x, int j) {
#pragma unroll
    for (int s = 0; s < KNB; ++s) {
        float ds1 = (s < KNB - 1) ? d[s + 1] : -FLT_BIG;
        int   is1 = (s < KNB - 1) ? ix[s + 1] : 0;
        bool cs  = x < d[s];
        bool cs1 = x < ds1;
        d[s]  = cs1 ? ds1 : (cs ? x : d[s]);
        ix[s] = cs1 ? is1 : (cs ? j : ix[s]);
    }
}

// ---- prep: pp[i] = (-2x, -2y, -2z, x^2+y^2+z^2)  (monotone distance key) ----
__global__ __launch_bounds__(256) void prep_pp(const float* __restrict__ pos,
                                               float4* __restrict__ pp) {
    const int i = blockIdx.x * 256 + threadIdx.x;
    const float x = pos[i * 3 + 0], y = pos[i * 3 + 1], z = pos[i * 3 + 2];
    pp[i] = make_float4(-2.f * x, -2.f * y, -2.f * z, fmaf(x, x, fmaf(y, y, z * z)));
}

// ---- Phase 1: per (query, chunk) top-16 distances via branchless med3 insert,
//      then capped rescan to recover indices (stored [row][query], coalesced). ----
__global__ __launch_bounds__(256) void knn_partial(const float* __restrict__ pos,
                                                   const float4* __restrict__ pp,
                                                   int* __restrict__ pi) {
    __shared__ float4 sm[CHUNK];   // 16 KB
    const int tid = threadIdx.x;
    const int qg  = blockIdx.x * 256 + tid;
    const int b   = qg >> 13;
    const int c   = blockIdx.y;
    const int j0  = c * CHUNK;

    for (int t = tid; t < CHUNK; t += 256) sm[t] = pp[b * N_PTS + j0 + t];
    __syncthreads();

    const float qx = pos[qg * 3 + 0], qy = pos[qg * 3 + 1], qz = pos[qg * 3 + 2];

    float d[KNB];
#pragma unroll
    for (int s = 0; s < KNB; ++s) d[s] = FLT_BIG;

#pragma unroll 8
    for (int t = 0; t < CHUNK; ++t) {
        const float4 v = sm[t];
        const float x = fmaf(qx, v.x, fmaf(qy, v.y, fmaf(qz, v.z, v.w)));
        // unconditional med3 sorted-insert: no-op when x >= d[0]
#pragma unroll
        for (int s = 0; s < KNB - 1; ++s) d[s] = med3f(d[s], d[s + 1], x);
        d[KNB - 1] = fminf(d[KNB - 1], x);
    }

    const float thr = d[0];          // 16th-smallest key in this chunk
    int cnt = 0;
    const size_t base = (size_t)(c * KNB) * NQ + qg;
#pragma unroll 4
    for (int t = 0; t < CHUNK; ++t) {
        const float4 v = sm[t];
        const float x = fmaf(qx, v.x, fmaf(qy, v.y, fmaf(qz, v.z, v.w)));
        if (x <= thr && cnt < KNB) {
            pi[base + (size_t)cnt * NQ] = j0 + t;   // within-batch point index
            ++cnt;
        }
    }
}

// ---- Merge stage A: 4 threads/query, each merges 2 chunks (32 cands) -> 16 ----
__global__ __launch_bounds__(256) void knn_mergeA(const float* __restrict__ pos,
                                                  const float4* __restrict__ pp,
                                                  const int* __restrict__ pi,
                                                  int* __restrict__ pi2) {
    const int gt = blockIdx.x * 256 + threadIdx.x;   // [0, NQ*4)
    const int qg = gt & (NQ - 1);
    const int m  = gt >> 14;                         // 0..3
    const int b  = qg >> 13;
    const float qx = pos[qg * 3 + 0], qy = pos[qg * 3 + 1], qz = pos[qg * 3 + 2];

    float d[KNB]; int ix[KNB];
#pragma unroll
    for (int s = 0; s < KNB; ++s) { d[s] = FLT_BIG; ix[s] = 0; }

#pragma unroll 4
    for (int r = 0; r < 2 * KNB; ++r) {
        const int j = pi[(size_t)(m * 2 * KNB + r) * NQ + qg];
        const float4 v = pp[b * N_PTS + j];
        const float x = fmaf(qx, v.x, fmaf(qy, v.y, fmaf(qz, v.z, v.w)));
        ins16(d, ix, x, j);
    }
#pragma unroll
    for (int s = 0; s < KNB; ++s) pi2[(size_t)(m * KNB + s) * NQ + qg] = ix[s];
}

// ---- Merge stage B: 1 thread/query, 64 cands -> final 16 ----
__global__ __launch_bounds__(256) void knn_mergeB(const float* __restrict__ pos,
                                                  const float4* __restrict__ pp,
                                                  const int* __restrict__ pi2,
                                                  int* __restrict__ knn) {
    const int qg = blockIdx.x * 256 + threadIdx.x;
    const int b  = qg >> 13;
    const float qx = pos[qg * 3 + 0], qy = pos[qg * 3 + 1], qz = pos[qg * 3 + 2];

    float d[KNB]; int ix[KNB];
#pragma unroll
    for (int s = 0; s < KNB; ++s) { d[s] = FLT_BIG; ix[s] = 0; }

#pragma unroll 4
    for (int r = 0; r < 4 * KNB; ++r) {
        const int j = pi2[(size_t)r * NQ + qg];
        const float4 v = pp[b * N_PTS + j];
        const float x = fmaf(qx, v.x, fmaf(qy, v.y, fmaf(qz, v.z, v.w)));
        ins16(d, ix, x, j);
    }
#pragma unroll
    for (int s = 0; s < KNB; ++s) knn[(size_t)qg * KNB + s] = ix[s];
}

// ---- per-edge MLPs: one thread per (query, neighbor) ----
__global__ __launch_bounds__(256) void pt_edge(const float* __restrict__ hin,
                                               const float* __restrict__ pos,
                                               const int* __restrict__ knn,
                                               const float* __restrict__ wqkv,
                                               const float* __restrict__ pw1,
                                               const float* __restrict__ pb1,
                                               const float* __restrict__ pw2,
                                               const float* __restrict__ pb2,
                                               const float* __restrict__ aw1,
                                               const float* __restrict__ ab1,
                                               const float* __restrict__ aw2,
                                               const float* __restrict__ ab2,
                                               float* __restrict__ ebuf) {
    const int gt = blockIdx.x * 256 + threadIdx.x;   // [0, NQ*16)
    const int qg = gt >> 4;
    const int j  = gt & 15;
    const int b  = qg >> 13;
    const int jj = knn[qg * KNB + j];
    const int g  = b * N_PTS + jj;

    const float hi0 = hin[qg * 3 + 0], hi1 = hin[qg * 3 + 1], hi2 = hin[qg * 3 + 2];
    const float hj0 = hin[g * 3 + 0],  hj1 = hin[g * 3 + 1],  hj2 = hin[g * 3 + 2];
    const float rx = pos[qg * 3 + 0] - pos[g * 3 + 0];
    const float ry = pos[qg * 3 + 1] - pos[g * 3 + 1];
    const float rz = pos[qg * 3 + 2] - pos[g * 3 + 2];

    const float q0 = fmaf(hi0, wqkv[0], fmaf(hi1, wqkv[9],  hi2 * wqkv[18]));
    const float q1 = fmaf(hi0, wqkv[1], fmaf(hi1, wqkv[10], hi2 * wqkv[19]));
    const float q2 = fmaf(hi0, wqkv[2], fmaf(hi1, wqkv[11], hi2 * wqkv[20]));
    const float k0 = fmaf(hj0, wqkv[3], fmaf(hj1, wqkv[12], hj2 * wqkv[21]));
    const float k1 = fmaf(hj0, wqkv[4], fmaf(hj1, wqkv[13], hj2 * wqkv[22]));
    const float k2 = fmaf(hj0, wqkv[5], fmaf(hj1, wqkv[14], hj2 * wqkv[23]));
    const float v0 = fmaf(hj0, wqkv[6], fmaf(hj1, wqkv[15], hj2 * wqkv[24]));
    const float v1 = fmaf(hj0, wqkv[7], fmaf(hj1, wqkv[16], hj2 * wqkv[25]));
    const float v2 = fmaf(hj0, wqkv[8], fmaf(hj1, wqkv[17], hj2 * wqkv[26]));

    float e0 = pb2[0], e1 = pb2[1], e2 = pb2[2];
#pragma unroll
    for (int hh = 0; hh < 32; ++hh) {
        float t = fmaf(rx, pw1[hh], fmaf(ry, pw1[32 + hh], fmaf(rz, pw1[64 + hh], pb1[hh])));
        t = fmaxf(t, 0.0f);
        e0 = fmaf(t, pw2[hh * 3 + 0], e0);
        e1 = fmaf(t, pw2[hh * 3 + 1], e1);
        e2 = fmaf(t, pw2[hh * 3 + 2], e2);
    }

    const float x0 = q0 - k0 + e0;
    const float x1 = q1 - k1 + e1;
    const float x2 = q2 - k2 + e2;

    float s0 = ab2[0], s1 = ab2[1], s2 = ab2[2];
#pragma unroll
    for (int hh = 0; hh < 12; ++hh) {
        float t = fmaf(x0, aw1[hh], fmaf(x1, aw1[12 + hh], fmaf(x2, aw1[24 + hh], ab1[hh])));
        t = fmaxf(t, 0.0f);
        s0 = fmaf(t, aw2[hh * 3 + 0], s0);
        s1 = fmaf(t, aw2[hh * 3 + 1], s1);
        s2 = fmaf(t, aw2[hh * 3 + 2], s2);
    }

    float* eb = ebuf + (size_t)gt * 6;
    eb[0] = s0; eb[1] = s1; eb[2] = s2;
    eb[3] = v0 + e0; eb[4] = v1 + e1; eb[5] = v2 + e2;
}

// ---- per-point: softmax over 16 neighbors + aggregate + sigmoid (+ final head) ----
__global__ __launch_bounds__(256) void pt_point(const float* __restrict__ ebuf,
                                                float* __restrict__ hout,
                                                const float* __restrict__ lw,
                                                const float* __restrict__ lb,
                                                float* __restrict__ out,
                                                int last) {
    const int qg = blockIdx.x * 256 + threadIdx.x;
    const float4* eb = (const float4*)(ebuf + (size_t)qg * 96);
    float f[96];
#pragma unroll
    for (int v = 0; v < 24; ++v) {
        const float4 t = eb[v];
        f[v * 4 + 0] = t.x; f[v * 4 + 1] = t.y; f[v * 4 + 2] = t.z; f[v * 4 + 3] = t.w;
    }

    float hnew[3];
#pragma unroll
    for (int dch = 0; dch < 3; ++dch) {
        float m = f[dch];
#pragma unroll
        for (int j = 1; j < KNB; ++j) m = fmaxf(m, f[j * 6 + dch]);
        float den = 0.f, acc = 0.f;
#pragma unroll
        for (int j = 0; j < KNB; ++j) {
            const float ex = __expf(f[j * 6 + dch] - m);
            den += ex;
            acc = fmaf(ex, f[j * 6 + 3 + dch], acc);
        }
        const float a = acc / den;
        hnew[dch] = 1.f / (1.f + __expf(-a));
    }

    if (!last) {
        hout[qg * 3 + 0] = hnew[0];
        hout[qg * 3 + 1] = hnew[1];
        hout[qg * 3 + 2] = hnew[2];
    } else {
        const float o0 = fmaf(hnew[0], lw[0], fmaf(hnew[1], lw[2], fmaf(hnew[2], lw[4], lb[0])));
        const float o1 = fmaf(hnew[0], lw[1], fmaf(hnew[1], lw[3], fmaf(hnew[2], lw[5], lb[1])));
        const float mm = fmaxf(o0, o1);
        const float e0 = __expf(o0 - mm), e1 = __expf(o1 - mm);
        const float inv = 1.f / (e0 + e1);
        out[qg * 2 + 0] = e0 * inv;
        out[qg * 2 + 1] = e1 * inv;
    }
}

// ---------------- launch ----------------
extern "C" void kernel_launch(void* const* d_in, const int* in_sizes, int n_in,
                              void* d_out, int out_size, void* d_ws, size_t ws_size,
                              hipStream_t stream) {
    const float* feats = (const float*)d_in[0];
    const float* pos   = (const float*)d_in[1];
    const float* wqkv = (const float*)d_in[3];
    const float* pw1  = (const float*)d_in[4];
    const float* pb1  = (const float*)d_in[5];
    const float* pw2  = (const float*)d_in[6];
    const float* pb2  = (const float*)d_in[7];
    const float* aw1  = (const float*)d_in[8];
    const float* ab1  = (const float*)d_in[9];
    const float* aw2  = (const float*)d_in[10];
    const float* ab2  = (const float*)d_in[11];
    const float* lw   = (const float*)d_in[12];
    const float* lb   = (const float*)d_in[13];
    float* out = (float*)d_out;

    // workspace layout (ebuf aliases pi: pi is dead after mergeA)
    const size_t pp_bytes  = (size_t)NQ * 4 * 4;                  // 256 KB
    const size_t pi_bytes  = (size_t)NCHUNK * KNB * NQ * 4;       // 8 MB (>= ebuf 6.3 MB)
    const size_t pi2_bytes = (size_t)4 * KNB * NQ * 4;            // 4 MB
    const size_t knn_bytes = (size_t)NQ * KNB * 4;                // 1 MB
    const size_t h_bytes   = (size_t)NQ * 3 * 4;                  // 192 KB
    if (ws_size < pp_bytes + pi_bytes + pi2_bytes + knn_bytes + 2 * h_bytes) return;

    char* ws = (char*)d_ws;
    float4* pp  = (float4*)ws;
    int*    pi  = (int*)(ws + pp_bytes);
    float*  ebuf = (float*)(ws + pp_bytes);                        // alias of pi region
    int*    pi2 = (int*)(ws + pp_bytes + pi_bytes);
    int*    knn = (int*)(ws + pp_bytes + pi_bytes + pi2_bytes);
    float*  hA  = (float*)(ws + pp_bytes + pi_bytes + pi2_bytes + knn_bytes);
    float*  hB  = hA + (size_t)NQ * 3;

    prep_pp<<<NQ / 256, 256, 0, stream>>>(pos, pp);
    dim3 g1(NQ / 256, NCHUNK);
    knn_partial<<<g1, 256, 0, stream>>>(pos, pp, pi);
    knn_mergeA<<<NQ * 4 / 256, 256, 0, stream>>>(pos, pp, pi, pi2);
    knn_mergeB<<<NQ / 256, 256, 0, stream>>>(pos, pp, pi2, knn);

    // layer 0: feats -> hA
    pt_edge<<<NQ * 16 / 256, 256, 0, stream>>>(feats, pos, knn,
        wqkv + 0, pw1 + 0, pb1 + 0, pw2 + 0, pb2 + 0,
        aw1 + 0, ab1 + 0, aw2 + 0, ab2 + 0, ebuf);
    pt_point<<<NQ / 256, 256, 0, stream>>>(ebuf, hA, lw, lb, out, 0);
    // layer 1: hA -> hB
    pt_edge<<<NQ * 16 / 256, 256, 0, stream>>>(hA, pos, knn,
        wqkv + 27, pw1 + 96, pb1 + 32, pw2 + 96, pb2 + 3,
        aw1 + 36, ab1 + 12, aw2 + 36, ab2 + 3, ebuf);
    pt_point<<<NQ / 256, 256, 0, stream>>>(ebuf, hB, lw, lb, out, 0);
    // layer 2: hB -> out
    pt_edge<<<NQ * 16 / 256, 256, 0, stream>>>(hB, pos, knn,
        wqkv + 54, pw1 + 192, pb1 + 64, pw2 + 192, pb2 + 6,
        aw1 + 72, ab1 + 24, aw2 + 72, ab2 + 6, ebuf);
    pt_point<<<NQ / 256, 256, 0, stream>>>(ebuf, hB, lw, lb, out, 1);
}